// Round 2
// baseline (1389.278 us; speedup 1.0000x reference)
//
#include <hip/hip_runtime.h>
#include <stdint.h>
#include <math.h>

#define T_SIM 500
#define NB    64
#define NIN   1024
#define NHID  1024
#define NOUT  10
#define KSRM  77     // SRM kernel taps 0..76 (srm[0] == 0)
#define CHUNK 16     // batches per chunk for layer-1 pipeline

// Reference builds kernels in python f64, then rounds to fp32. We reproduce
// the exact fp32 tap values and promote to f64 for all arithmetic.
__device__ __forceinline__ double srm_tap(int k) {
  // mult*t/tau*exp(1 - t/tau), mult=1, tau=10, t=k
  double u = (double)k / 10.0;
  double v = u * exp(1.0 - u);
  return (double)(float)v;
}
__device__ __forceinline__ double ref_tap(int j) {
  // mult=-2*theta=-20, tau=1, t=j
  double v = (-20.0 * (double)j) * exp(1.0 - (double)j);
  return (double)(float)v;
}

// ---------------------------------------------------------------------------
// K0: pack binary input spikes x[b][i][t] (fp32 0/1) -> bits [b][t][16 x u64]
// grid (64, 16, 5), block 64 (one wave).
__global__ __launch_bounds__(64)
void k_pack(const float* __restrict__ x, unsigned long long* __restrict__ bits) {
  const int b = blockIdx.x, ig = blockIdx.y, tc = blockIdx.z;
  const int lane = threadIdx.x;
  const float* xr = x + ((size_t)b * NIN + ig * 64 + lane) * T_SIM;
  const int t0 = tc * 100;
  for (int t = t0; t < t0 + 100; t += 4) {
    const float4 v = *(const float4*)(xr + t);
    unsigned long long m0 = __ballot(v.x > 0.5f);
    unsigned long long m1 = __ballot(v.y > 0.5f);
    unsigned long long m2 = __ballot(v.z > 0.5f);
    unsigned long long m3 = __ballot(v.w > 0.5f);
    if (lane == 0) {
      unsigned long long* w = bits + (size_t)(b * T_SIM + t) * 16 + ig;
      w[0] = m0; w[16] = m1; w[32] = m2; w[48] = m3;
    }
  }
}

// ---------------------------------------------------------------------------
// K0b: W1[o][i] -> W1T[i][o] fp32, tiled 64x64 through LDS.
__global__ __launch_bounds__(256)
void k_transpose(const float* __restrict__ W1, float* __restrict__ W1T) {
  __shared__ float tile[64][65];
  const int bo = blockIdx.x * 64, bi = blockIdx.y * 64;
  for (int k = threadIdx.x; k < 4096; k += 256) {
    int r = k >> 6, c = k & 63;
    tile[r][c] = W1[(size_t)(bo + r) * NIN + bi + c];
  }
  __syncthreads();
  for (int k = threadIdx.x; k < 4096; k += 256) {
    int r = k >> 6, c = k & 63;
    W1T[(size_t)(bi + r) * NHID + bo + c] = tile[c][r];
  }
}

// ---------------------------------------------------------------------------
// K1: dense1 sparse gather, f64 accumulation of fp32 weights.
// grid (CHUNK*500, 2), block 128. a1c layout [b_loc*500+t][1024] f64.
__global__ __launch_bounds__(128)
void k_dense1(const uint32_t* __restrict__ bits, const float* __restrict__ W1T,
              double* __restrict__ a1c, int col_base) {
  const int col_loc = blockIdx.x;
  const int half = blockIdx.y;
  const int o = half * 512 + threadIdx.x * 4;
  const uint32_t* w = bits + (size_t)(col_base + col_loc) * 32;
  double a0 = 0.0, a1 = 0.0, a2 = 0.0, a3 = 0.0;
  for (int wi = 0; wi < 32; ++wi) {
    uint32_t m = w[wi];            // wave-uniform
    const int ibase = wi * 32;
    while (m) {
      const int j = __ffs(m) - 1;
      m &= m - 1;
      const float4 wv = *(const float4*)(W1T + (size_t)(ibase + j) * NHID + o);
      a0 += (double)wv.x; a1 += (double)wv.y; a2 += (double)wv.z; a3 += (double)wv.w;
    }
  }
  double4 r; r.x = a0; r.y = a1; r.z = a2; r.w = a3;
  *(double4*)(a1c + (size_t)col_loc * NHID + o) = r;
}

// ---------------------------------------------------------------------------
// K2: psp layer1 — direct 77-tap FIR with fp32-rounded taps, f64 math.
// Block: 256 threads = 64 neurons x 4 t-quarters; tile = 64 n x 64 t.
// grid (16 ngroups, CHUNK batches, 8 t-tiles).
#define TT 64
__global__ __launch_bounds__(256)
void k_psp1(const double* __restrict__ a1c, double* __restrict__ y1c) {
  __shared__ double S[(TT + 76) * 64];   // 140 x 64 doubles = 71680 B
  __shared__ double srm[KSRM];
  const int ng = blockIdx.x;
  const int b  = blockIdx.y;
  const int t0 = blockIdx.z * TT;
  const int tid = threadIdx.x;
  if (tid < KSRM) srm[tid] = srm_tap(tid);
  for (int idx = tid; idx < (TT + 76) * 64; idx += 256) {
    const int r = idx >> 6, c = idx & 63;
    const int t = t0 - 76 + r;
    double v = 0.0;
    if (t >= 0 && t < T_SIM)
      v = a1c[((size_t)b * T_SIM + t) * NHID + ng * 64 + c];
    S[idx] = v;
  }
  __syncthreads();
  const int n = tid & 63, tq = tid >> 6;
  for (int c = 0; c < 4; ++c) {
    const int tl = tq * 16 + c * 4;      // local t of first of 4 outputs
    double acc0 = 0.0, acc1 = 0.0, acc2 = 0.0, acc3 = 0.0;
#pragma unroll
    for (int s = 0; s < 80; ++s) {
      const double v = S[(tl + s) * 64 + n];
      const int k0 = 76 - s;
      const int k1 = 77 - s;
      const int k2 = 78 - s;
      const int k3 = 79 - s;
      if (k0 >= 0 && k0 < KSRM) acc0 += srm[k0] * v;
      if (k1 >= 0 && k1 < KSRM) acc1 += srm[k1] * v;
      if (k2 >= 0 && k2 < KSRM) acc2 += srm[k2] * v;
      if (k3 >= 0 && k3 < KSRM) acc3 += srm[k3] * v;
    }
    const int tg = t0 + tl;
    double* yb = y1c + (size_t)b * T_SIM * NHID + ng * 64 + n;
    if (tg + 0 < T_SIM) yb[(size_t)(tg + 0) * NHID] = acc0;
    if (tg + 1 < T_SIM) yb[(size_t)(tg + 1) * NHID] = acc1;
    if (tg + 2 < T_SIM) yb[(size_t)(tg + 2) * NHID] = acc2;
    if (tg + 3 < T_SIM) yb[(size_t)(tg + 3) * NHID] = acc3;
  }
}

// ---------------------------------------------------------------------------
// K3: LIF refractory scan layer1 (f64) + ballot pack of s1.
// grid (CHUNK, 4), block 256. Thread = neuron (b, o).
__global__ __launch_bounds__(256)
void k_spike1(const double* __restrict__ y1c, unsigned long long* __restrict__ s1bits,
              int b_base) {
  const int b_loc = blockIdx.x;
  const int otile = blockIdx.y;
  const int o = otile * 256 + threadIdx.x;
  const int lane = threadIdx.x & 63;
  const int wv = threadIdx.x >> 6;
  const double* in = y1c + (size_t)b_loc * T_SIM * NHID + o;
  unsigned long long* outw =
      s1bits + (size_t)(b_base + b_loc) * T_SIM * 16 + otile * 4 + wv;

  double ref[11];
#pragma unroll
  for (int j = 1; j <= 10; ++j) ref[j] = ref_tap(j);
  uint32_t smask = 0;

  for (int t0 = 0; t0 < T_SIM; t0 += 10) {
    double cur[10];
#pragma unroll
    for (int g = 0; g < 10; ++g) cur[g] = in[(size_t)(t0 + g) * NHID];
#pragma unroll
    for (int g = 0; g < 10; ++g) {
      double u = cur[g];
      // oldest spike's contribution added first (matches reference buf order)
#pragma unroll
      for (int j = 10; j >= 1; --j)
        u += ref[j] * (double)((smask >> (j - 1)) & 1u);
      const bool sp = (u >= 10.0);
      smask = (smask << 1) | (sp ? 1u : 0u);
      const unsigned long long bm = __ballot(sp);
      if (lane == 0) outw[(size_t)(t0 + g) * 16] = bm;
    }
  }
}

// ---------------------------------------------------------------------------
// K4: dense2 sparse gather from s1 bits, W2 fp32 in LDS, f64 acc.
// grid 125, block 256: thread = one (b,t) column.
__global__ __launch_bounds__(256)
void k_dense2(const unsigned long long* __restrict__ s1bits,
              const float* __restrict__ W2, double* __restrict__ a2) {
  __shared__ float w2t[NHID * NOUT];  // 40 KB, [i][o]
  for (int k = threadIdx.x; k < NHID * NOUT; k += 256) {
    const int o = k >> 10, i = k & 1023;
    w2t[i * NOUT + o] = W2[k];
  }
  __syncthreads();
  const int col = blockIdx.x * 256 + threadIdx.x;  // 0..31999
  double acc[NOUT];
#pragma unroll
  for (int o = 0; o < NOUT; ++o) acc[o] = 0.0;
  const unsigned long long* w = s1bits + (size_t)col * 16;
  for (int wi = 0; wi < 16; ++wi) {
    unsigned long long m = w[wi];
    const int ibase = wi * 64;
    while (m) {
      const int j = __ffsll(m) - 1;
      m &= m - 1;
      const float* row = &w2t[(ibase + j) * NOUT];
#pragma unroll
      for (int o = 0; o < NOUT; ++o) acc[o] += (double)row[o];
    }
  }
  double* outp = a2 + (size_t)col * NOUT;
#pragma unroll
  for (int o = 0; o < NOUT; ++o) outp[o] = acc[o];
}

// ---------------------------------------------------------------------------
// K5: psp layer2 — whole batch [500][10] in LDS, 77-tap FIR, f64.
// grid 64, block 256.
__global__ __launch_bounds__(256)
void k_psp2(const double* __restrict__ a2, double* __restrict__ y2) {
  __shared__ double S[T_SIM * NOUT];   // 40 KB
  __shared__ double srm[KSRM];
  const int b = blockIdx.x;
  const int tid = threadIdx.x;
  if (tid < KSRM) srm[tid] = srm_tap(tid);
  for (int idx = tid; idx < T_SIM * NOUT; idx += 256)
    S[idx] = a2[(size_t)b * T_SIM * NOUT + idx];
  __syncthreads();
  for (int t = tid; t < T_SIM; t += 256) {
    double acc[NOUT];
#pragma unroll
    for (int o = 0; o < NOUT; ++o) acc[o] = 0.0;
    const int kmax = (t < KSRM - 1) ? t : (KSRM - 1);
    for (int k = 0; k <= kmax; ++k) {
      const double sk = srm[k];
      const double* row = &S[(t - k) * NOUT];
#pragma unroll
      for (int o = 0; o < NOUT; ++o) acc[o] += sk * row[o];
    }
    double* yp = y2 + ((size_t)b * T_SIM + t) * NOUT;
#pragma unroll
    for (int o = 0; o < NOUT; ++o) yp[o] = acc[o];
  }
}

// ---------------------------------------------------------------------------
// K6: LIF refractory scan layer2, writes final spikes [b][o][t] fp32.
// grid 10, block 64: thread = neuron (b, o), 640 total.
__global__ __launch_bounds__(64)
void k_spike2(const double* __restrict__ y2, float* __restrict__ out) {
  const int idx = blockIdx.x * 64 + threadIdx.x;  // 0..639
  const int b = idx / NOUT, o = idx % NOUT;
  const double* in = y2 + (size_t)b * T_SIM * NOUT + o;
  float* op = out + ((size_t)b * NOUT + o) * T_SIM;

  double ref[11];
#pragma unroll
  for (int j = 1; j <= 10; ++j) ref[j] = ref_tap(j);
  uint32_t smask = 0;

  for (int t0 = 0; t0 < T_SIM; t0 += 10) {
    double cur[10];
#pragma unroll
    for (int g = 0; g < 10; ++g) cur[g] = in[(size_t)(t0 + g) * NOUT];
#pragma unroll
    for (int g = 0; g < 10; ++g) {
      double u = cur[g];
#pragma unroll
      for (int j = 10; j >= 1; --j)
        u += ref[j] * (double)((smask >> (j - 1)) & 1u);
      const bool sp = (u >= 10.0);
      smask = (smask << 1) | (sp ? 1u : 0u);
      op[t0 + g] = sp ? 1.0f : 0.0f;
    }
  }
}

// ---------------------------------------------------------------------------
extern "C" void kernel_launch(void* const* d_in, const int* in_sizes, int n_in,
                              void* d_out, int out_size, void* d_ws, size_t ws_size,
                              hipStream_t stream) {
  const float* x  = (const float*)d_in[0];   // [64][1024][500]
  const float* W1 = (const float*)d_in[1];   // [1024][1024]
  const float* W2 = (const float*)d_in[2];   // [10][1024]
  float* out = (float*)d_out;                // [64][10][500]

  char* ws = (char*)d_ws;
  unsigned long long* bits1 = (unsigned long long*)(ws);              // 4,096,000
  float*  W1T = (float*) (ws + 4096000);                              // 4,194,304
  double* a1c = (double*)(ws + 8290304);                              // 65,536,000
  double* y1c = (double*)(ws + 73826304);                             // 65,536,000
  unsigned long long* s1bits = (unsigned long long*)(ws + 139362304); // 4,096,000
  double* a2  = (double*)(ws + 143458304);                            // 2,560,000
  double* y2  = (double*)(ws + 146018304);                            // 2,560,000
  // total ws use: 148,578,304 B

  hipLaunchKernelGGL(k_pack, dim3(NB, 16, 5), dim3(64), 0, stream, x, bits1);
  hipLaunchKernelGGL(k_transpose, dim3(16, 16), dim3(256), 0, stream, W1, W1T);

  for (int bc = 0; bc < NB; bc += CHUNK) {
    hipLaunchKernelGGL(k_dense1, dim3(CHUNK * T_SIM, 2), dim3(128), 0, stream,
                       (const uint32_t*)bits1, W1T, a1c, bc * T_SIM);
    hipLaunchKernelGGL(k_psp1, dim3(16, CHUNK, 8), dim3(256), 0, stream, a1c, y1c);
    hipLaunchKernelGGL(k_spike1, dim3(CHUNK, 4), dim3(256), 0, stream,
                       y1c, s1bits, bc);
  }

  hipLaunchKernelGGL(k_dense2, dim3(125), dim3(256), 0, stream, s1bits, W2, a2);
  hipLaunchKernelGGL(k_psp2, dim3(NB), dim3(256), 0, stream, a2, y2);
  hipLaunchKernelGGL(k_spike2, dim3(10), dim3(64), 0, stream, y2, out);
}

// Round 3
// 1054.082 us; speedup vs baseline: 1.3180x; 1.3180x over previous
//
#include <hip/hip_runtime.h>
#include <stdint.h>
#include <math.h>

#define T_SIM 500
#define NB    64
#define NIN   1024
#define NHID  1024
#define NOUT  10
#define KSRM  77     // SRM kernel taps 0..76 (srm[0] == 0)
#define CHUNK 32     // batches per chunk for layer-1 pipeline
#define TT    32     // t-tile inside fused psp+spike kernel
#define RING  108    // TT + 76 history rows

// Reference builds kernels in python f64 then rounds to fp32; we reproduce the
// exact fp32 tap values and do all accumulation in f64 (matched R2: absmax 0).
__device__ __forceinline__ double srm_tap(int k) {
  double u = (double)k / 10.0;
  double v = u * exp(1.0 - u);
  return (double)(float)v;
}
__device__ __forceinline__ double ref_tap(int j) {
  double v = (-20.0 * (double)j) * exp(1.0 - (double)j);
  return (double)(float)v;
}

// ---------------------------------------------------------------------------
// K0: pack binary input spikes x[b][i][t] (fp32 0/1) -> bits [b][t][16 x u64]
__global__ __launch_bounds__(64)
void k_pack(const float* __restrict__ x, unsigned long long* __restrict__ bits) {
  const int b = blockIdx.x, ig = blockIdx.y, tc = blockIdx.z;
  const int lane = threadIdx.x;
  const float* xr = x + ((size_t)b * NIN + ig * 64 + lane) * T_SIM;
  const int t0 = tc * 100;
  for (int t = t0; t < t0 + 100; t += 4) {
    const float4 v = *(const float4*)(xr + t);
    unsigned long long m0 = __ballot(v.x > 0.5f);
    unsigned long long m1 = __ballot(v.y > 0.5f);
    unsigned long long m2 = __ballot(v.z > 0.5f);
    unsigned long long m3 = __ballot(v.w > 0.5f);
    if (lane == 0) {
      unsigned long long* w = bits + (size_t)(b * T_SIM + t) * 16 + ig;
      w[0] = m0; w[16] = m1; w[32] = m2; w[48] = m3;
    }
  }
}

// ---------------------------------------------------------------------------
// K0b: W1[o][i] -> W1T[i][o] fp32, tiled 64x64 through LDS.
__global__ __launch_bounds__(256)
void k_transpose(const float* __restrict__ W1, float* __restrict__ W1T) {
  __shared__ float tile[64][65];
  const int bo = blockIdx.x * 64, bi = blockIdx.y * 64;
  for (int k = threadIdx.x; k < 4096; k += 256) {
    int r = k >> 6, c = k & 63;
    tile[r][c] = W1[(size_t)(bo + r) * NIN + bi + c];
  }
  __syncthreads();
  for (int k = threadIdx.x; k < 4096; k += 256) {
    int r = k >> 6, c = k & 63;
    W1T[(size_t)(bi + r) * NHID + bo + c] = tile[c][r];
  }
}

// ---------------------------------------------------------------------------
// K1: dense1 sparse gather, f64 accumulation of fp32 weights.
// grid (CHUNK*500, 2), block 128. a1c layout [b_loc*500+t][1024] f64.
__global__ __launch_bounds__(128)
void k_dense1(const uint32_t* __restrict__ bits, const float* __restrict__ W1T,
              double* __restrict__ a1c, int col_base) {
  const int col_loc = blockIdx.x;
  const int half = blockIdx.y;
  const int o = half * 512 + threadIdx.x * 4;
  const uint32_t* w = bits + (size_t)(col_base + col_loc) * 32;
  double a0 = 0.0, a1 = 0.0, a2 = 0.0, a3 = 0.0;
  for (int wi = 0; wi < 32; ++wi) {
    uint32_t m = w[wi];            // wave-uniform
    const int ibase = wi * 32;
    while (m) {
      const int j = __ffs(m) - 1;  // ascending i => deterministic sum order
      m &= m - 1;
      const float4 wv = *(const float4*)(W1T + (size_t)(ibase + j) * NHID + o);
      a0 += (double)wv.x; a1 += (double)wv.y; a2 += (double)wv.z; a3 += (double)wv.w;
    }
  }
  double4 r; r.x = a0; r.y = a1; r.z = a2; r.w = a3;
  *(double4*)(a1c + (size_t)col_loc * NHID + o) = r;
}

// ---------------------------------------------------------------------------
// K2: FUSED psp1 + spike1. Block = (neuron-group ng, batch b_loc); owns all
// 500 t. LDS ring buffer S carries FIR history across 32-t tiles (no halo
// re-read, no y1 round-trip). Wave 0 runs the refractory scan per tile.
// grid (16, CHUNK), block 256.  LDS: 108*64*8 + 32*64*8 + 77*8 = 72,296 B.
__global__ __launch_bounds__(256)
void k_ps1(const double* __restrict__ a1c, unsigned long long* __restrict__ s1bits,
           int b_base) {
  __shared__ double S[RING * 64];
  __shared__ double Y[TT * 64];
  __shared__ double srm[KSRM];
  const int ng = blockIdx.x, b_loc = blockIdx.y;
  const int tid = threadIdx.x;
  if (tid < KSRM) srm[tid] = srm_tap(tid);
  for (int i = tid; i < RING * 64; i += 256) S[i] = 0.0;

  double refk[11];
#pragma unroll
  for (int j = 1; j <= 10; ++j) refk[j] = ref_tap(j);
  uint32_t smask = 0;

  const double* abase = a1c + (size_t)b_loc * T_SIM * NHID + ng * 64;
  unsigned long long* sbase =
      s1bits + (size_t)(b_base + b_loc) * T_SIM * 16 + ng;

  __syncthreads();

  for (int t0 = 0; t0 < T_SIM; t0 += TT) {
    const int tv = (T_SIM - t0 < TT) ? (T_SIM - t0) : TT;
    // ---- load new rows into ring (coalesced: 64 consecutive n per row) ----
    for (int e = tid; e < tv * 64; e += 256) {
      const int r = e >> 6, n = e & 63;
      const int t = t0 + r;
      S[(t % RING) * 64 + n] = abase[(size_t)t * NHID + n];
    }
    __syncthreads();
    // ---- FIR: thread (n, tq) computes outputs t0+tq*8 .. +7 ----
    {
      const int n = tid & 63, tq = tid >> 6;
      const int tl0 = tq * 8;
      double acc[8];
#pragma unroll
      for (int u = 0; u < 8; ++u) acc[u] = 0.0;
      int t = t0 + tl0 - 76;
      int m = t % RING; if (m < 0) m += RING;
#pragma unroll
      for (int s = 0; s < 84; ++s) {
        if (t >= 0) {   // wave-uniform (depends on tq only)
          const double v = S[m * 64 + n];
#pragma unroll
          for (int u = 0; u < 8; ++u) {
            const int k = 76 - s + u;       // k descends 76->0: same order as R2
            if (k >= 0 && k < KSRM) acc[u] += srm[k] * v;
          }
        }
        ++t; ++m; if (m == RING) m = 0;
      }
#pragma unroll
      for (int u = 0; u < 8; ++u)
        if (tl0 + u < tv) Y[(tl0 + u) * 64 + n] = acc[u];
    }
    __syncthreads();
    // ---- refractory scan on wave 0 (thread = neuron n) ----
    if (tid < 64) {
      for (int g = 0; g < tv; ++g) {
        double u = Y[g * 64 + tid];
#pragma unroll
        for (int j = 10; j >= 1; --j)
          u += refk[j] * (double)((smask >> (j - 1)) & 1u);
        const bool sp = (u >= 10.0);
        smask = (smask << 1) | (sp ? 1u : 0u);
        const unsigned long long bm = __ballot(sp);
        if (tid == 0) sbase[(size_t)(t0 + g) * 16] = bm;
      }
    }
    __syncthreads();
  }
}

// ---------------------------------------------------------------------------
// K3: dense2 sparse gather from s1 bits, W2 fp32 in LDS, f64 acc. Full batch.
__global__ __launch_bounds__(256)
void k_dense2(const unsigned long long* __restrict__ s1bits,
              const float* __restrict__ W2, double* __restrict__ a2) {
  __shared__ float w2t[NHID * NOUT];  // 40 KB, [i][o]
  for (int k = threadIdx.x; k < NHID * NOUT; k += 256) {
    const int o = k >> 10, i = k & 1023;
    w2t[i * NOUT + o] = W2[k];
  }
  __syncthreads();
  const int col = blockIdx.x * 256 + threadIdx.x;  // 0..31999
  double acc[NOUT];
#pragma unroll
  for (int o = 0; o < NOUT; ++o) acc[o] = 0.0;
  const unsigned long long* w = s1bits + (size_t)col * 16;
  for (int wi = 0; wi < 16; ++wi) {
    unsigned long long m = w[wi];
    const int ibase = wi * 64;
    while (m) {
      const int j = __ffsll(m) - 1;
      m &= m - 1;
      const float* row = &w2t[(ibase + j) * NOUT];
#pragma unroll
      for (int o = 0; o < NOUT; ++o) acc[o] += (double)row[o];
    }
  }
  double* outp = a2 + (size_t)col * NOUT;
#pragma unroll
  for (int o = 0; o < NOUT; ++o) outp[o] = acc[o];
}

// ---------------------------------------------------------------------------
// K4: FUSED psp2 + spike2, one block per batch; whole [500][10] in LDS.
// LDS: 40000 + 40000 + 616 = 80,616 B. grid 64, block 256.
__global__ __launch_bounds__(256)
void k_l2(const double* __restrict__ a2, float* __restrict__ out) {
  __shared__ double S[T_SIM * NOUT];
  __shared__ double Y[T_SIM * NOUT];
  __shared__ double srm[KSRM];
  const int b = blockIdx.x, tid = threadIdx.x;
  if (tid < KSRM) srm[tid] = srm_tap(tid);
  for (int i = tid; i < T_SIM * NOUT; i += 256)
    S[i] = a2[(size_t)b * T_SIM * NOUT + i];
  __syncthreads();
  for (int i = tid; i < T_SIM * NOUT; i += 256) {
    const int t = i / 10, o = i - t * 10;
    const int kmax = (t < KSRM - 1) ? t : (KSRM - 1);
    double acc = 0.0;
    for (int k = 0; k <= kmax; ++k)   // k ascending: same order as R2 psp2
      acc += srm[k] * S[(t - k) * 10 + o];
    Y[i] = acc;
  }
  __syncthreads();
  if (tid < NOUT) {
    double refk[11];
#pragma unroll
    for (int j = 1; j <= 10; ++j) refk[j] = ref_tap(j);
    uint32_t smask = 0;
    float* op = out + ((size_t)b * NOUT + tid) * T_SIM;
    for (int t = 0; t < T_SIM; ++t) {
      double u = Y[t * 10 + tid];
#pragma unroll
      for (int j = 10; j >= 1; --j)
        u += refk[j] * (double)((smask >> (j - 1)) & 1u);
      const bool sp = (u >= 10.0);
      smask = (smask << 1) | (sp ? 1u : 0u);
      op[t] = sp ? 1.0f : 0.0f;
    }
  }
}

// ---------------------------------------------------------------------------
extern "C" void kernel_launch(void* const* d_in, const int* in_sizes, int n_in,
                              void* d_out, int out_size, void* d_ws, size_t ws_size,
                              hipStream_t stream) {
  const float* x  = (const float*)d_in[0];   // [64][1024][500]
  const float* W1 = (const float*)d_in[1];   // [1024][1024]
  const float* W2 = (const float*)d_in[2];   // [10][1024]
  float* out = (float*)d_out;                // [64][10][500]

  char* ws = (char*)d_ws;
  unsigned long long* bits1 = (unsigned long long*)(ws);              // 4,096,000
  float*  W1T = (float*) (ws + 4096000);                              // 4,194,304
  double* a1c = (double*)(ws + 8290304);                              // 131,072,000 (CHUNK=32)
  unsigned long long* s1bits = (unsigned long long*)(ws + 139362304); // 4,096,000
  double* a2  = (double*)(ws + 143458304);                            // 2,560,000
  // total ws use: 146,018,304 B (<= 148.5 MB proven in R2)

  hipLaunchKernelGGL(k_pack, dim3(NB, 16, 5), dim3(64), 0, stream, x, bits1);
  hipLaunchKernelGGL(k_transpose, dim3(16, 16), dim3(256), 0, stream, W1, W1T);

  for (int bc = 0; bc < NB; bc += CHUNK) {
    hipLaunchKernelGGL(k_dense1, dim3(CHUNK * T_SIM, 2), dim3(128), 0, stream,
                       (const uint32_t*)bits1, W1T, a1c, bc * T_SIM);
    hipLaunchKernelGGL(k_ps1, dim3(16, CHUNK), dim3(256), 0, stream,
                       a1c, s1bits, bc);
  }

  hipLaunchKernelGGL(k_dense2, dim3(125), dim3(256), 0, stream, s1bits, W2, a2);
  hipLaunchKernelGGL(k_l2, dim3(NB), dim3(256), 0, stream, a2, out);
}